// Round 14
// baseline (331.107 us; speedup 1.0000x reference)
//
#include <hip/hip_runtime.h>
#include <hip/hip_bf16.h>
#include <math.h>

// SurfaceAbstraction: gather(32 nbrs) -> 73-dim -> 3x(1x1 conv + batch BN +
// relu) -> maxpool. BN stats => 3 recompute passes. bf16 feature table +
// packed cn table (L2-resident gather), single-bf16 weights.
// R14: conv0 A-fragments load DIRECTLY from fb (lane (ln,kg) reads 16B at
// fb + j*64 + kt*32 + kg*8, j = gidx[m0*32+mt*16+ln]) -- no staging, no
// barrier for the feature part. Only geometry (k=64..79) stages via LDS
// (64 x 20-short rows + per-mt skew = conflict-free); k=80..95 weights are
// zero so kg>=2 passes a zero fragment. LDS 24->5/13/21KB. X2 in own buffer.

typedef __attribute__((ext_vector_type(8))) short short8;
typedef __attribute__((ext_vector_type(4))) float f32x4;

constexpr int NS = 32;
constexpr int GRID01 = 1280;   // S0/S1: 5 blocks/CU
constexpr int GRID2  = 1024;   // S2: 4 blocks/CU
constexpr float BN_EPS = 1e-5f;
constexpr float INV_PI  = 0.31830988618379067f;
constexpr float INV_2PI = 0.15915494309189535f;

__device__ __forceinline__ short cvt_bf16(float f) {
    unsigned u = __float_as_uint(f);
    u = (u + 0x7FFFu + ((u >> 16) & 1u)) >> 16;
    return (short)u;
}

// feature (fp32) -> bf16 table
__global__ __launch_bounds__(256) void feat2bf(
    const float* __restrict__ feature, short* __restrict__ fb, int n8)
{
    int i = blockIdx.x * 256 + threadIdx.x;
    if (i >= n8) return;
    const float4* src = (const float4*)(feature + (size_t)i * 8);
    float4 a = src[0], b = src[1];
    short8 v;
    v[0]=cvt_bf16(a.x); v[1]=cvt_bf16(a.y); v[2]=cvt_bf16(a.z); v[3]=cvt_bf16(a.w);
    v[4]=cvt_bf16(b.x); v[5]=cvt_bf16(b.y); v[6]=cvt_bf16(b.z); v[7]=cvt_bf16(b.w);
    *(short8*)(fb + (size_t)i * 8) = v;
}

// packed per-point table: [cx,cy,cz,nx | ny,nz,0,0] fp32
__global__ __launch_bounds__(256) void prep_cn(
    const float* __restrict__ center, const float* __restrict__ normal,
    float* __restrict__ cn, int N)
{
    int i = blockIdx.x * 256 + threadIdx.x;
    if (i >= N) return;
    float4 a, b;
    a.x = center[i*3+0]; a.y = center[i*3+1]; a.z = center[i*3+2];
    a.w = normal[i*3+0];
    b.x = normal[i*3+1]; b.y = normal[i*3+2]; b.z = 0.f; b.w = 0.f;
    *(float4*)(cn + (size_t)i * 8)     = a;
    *(float4*)(cn + (size_t)i * 8 + 4) = b;
}

// Weight fragments: frag(kt,nt), lane l holds W[n=nt*16+(l&15)][k=kt*32+(l>>4)*8+j]
// single bf16. conv0 K map: kn<64 -> orig 9+kn (feat); 64..69 -> orig 0..5;
// 70 -> orig 6 (nx); 72 -> orig 7 (ny); 73 -> orig 8 (nz); 71, 74..95 -> 0.
__global__ __launch_bounds__(256) void prep_weights(
    const float* __restrict__ w0, const float* __restrict__ w1,
    const float* __restrict__ w2,
    short* __restrict__ wf0, short* __restrict__ wf1, short* __restrict__ wf2)
{
    int i = blockIdx.x * 256 + threadIdx.x;
    int l = i & 63;
    int f = i >> 6;
    float vals[8];
    short* dh;
    if (f < 12) {
        int kt = f >> 2, nt = f & 3;
        int n = nt * 16 + (l & 15);
        int k0 = kt * 32 + (l >> 4) * 8;
        for (int j = 0; j < 8; ++j) {
            int kn = k0 + j;
            float v;
            if (kn < 64)       v = w0[n * 73 + 9 + kn];
            else if (kn < 70)  v = w0[n * 73 + (kn - 64)];
            else if (kn == 70) v = w0[n * 73 + 6];
            else if (kn == 72) v = w0[n * 73 + 7];
            else if (kn == 73) v = w0[n * 73 + 8];
            else v = 0.f;
            vals[j] = v;
        }
        dh = wf0 + (size_t)f * 512 + l * 8;
    } else if (f < 20) {
        int ff = f - 12;
        int kt = ff >> 2, nt = ff & 3;
        int n = nt * 16 + (l & 15);
        int k0 = kt * 32 + (l >> 4) * 8;
        for (int j = 0; j < 8; ++j) vals[j] = w1[n * 64 + k0 + j];
        dh = wf1 + (size_t)ff * 512 + l * 8;
    } else if (f < 36) {
        int ff = f - 20;
        int kt = ff >> 3, nt = ff & 7;
        int n = nt * 16 + (l & 15);
        int k0 = kt * 32 + (l >> 4) * 8;
        for (int j = 0; j < 8; ++j) vals[j] = w2[n * 64 + k0 + j];
        dh = wf2 + (size_t)ff * 512 + l * 8;
    } else return;
    for (int j = 0; j < 8; ++j) dh[j] = cvt_bf16(vals[j]);
}

template <int STAGE>
__global__ __launch_bounds__(256, (STAGE == 2 ? 4 : 5)) void stage_kernel(
    const float* __restrict__ center, const float* __restrict__ normal,
    const float* __restrict__ feature, const short* __restrict__ fb,
    const float* __restrict__ cn, const int* __restrict__ gidx,
    const short* __restrict__ wf0, const short* __restrict__ wf1,
    const short* __restrict__ wf2,
    const float* __restrict__ b0, const float* __restrict__ b1,
    const float* __restrict__ b2,
    const float* __restrict__ g0, const float* __restrict__ be0,
    const float* __restrict__ g1, const float* __restrict__ be1,
    const float* __restrict__ fstats, float* __restrict__ part,
    float* __restrict__ ymax, float* __restrict__ ymin,
    int ntiles, float inv_cnt)
{
    // Xg: geometry only, 64 rows x 20 shorts (40B stride, conflict-free)
    __shared__ __align__(16) short Xg[64 * 20 + 16];
    __shared__ __align__(16) short X1s[(STAGE >= 1) ? 64 * 64 : 16];
    __shared__ __align__(16) short X2s[(STAGE == 2) ? 64 * 64 : 16];

    const int t    = threadIdx.x;
    const int lane = t & 63;
    const int wv   = __builtin_amdgcn_readfirstlane(t >> 6);
    const int ln   = lane & 15;
    const int kg   = lane >> 4;
    const int rs   = ln & 7;
    const int chW  = wv * 16 + ln;

    // ---- weight fragments in registers (single bf16) ----
    short8 W0[3];
#pragma unroll
    for (int kt = 0; kt < 3; ++kt)
        W0[kt] = *(const short8*)(wf0 + (size_t)((kt*4 + wv) * 64 + lane) * 8);
    short8 W1[2];
    if constexpr (STAGE >= 1) {
#pragma unroll
        for (int kt = 0; kt < 2; ++kt)
            W1[kt] = *(const short8*)(wf1 + (size_t)((kt*4 + wv) * 64 + lane) * 8);
    }
    short8 W2[2][2];
    if constexpr (STAGE == 2) {
#pragma unroll
        for (int nti = 0; nti < 2; ++nti)
#pragma unroll
            for (int kt = 0; kt < 2; ++kt) {
                int ff = kt * 8 + (wv * 2 + nti);
                W2[nti][kt] = *(const short8*)(wf2 + (size_t)(ff * 64 + lane) * 8);
            }
    }

    // ---- biases / BN consts (per-lane; channel fixed) ----
    const float bb0 = b0[chW];
    float bb1 = 0.f, bb2a = 0.f, bb2b = 0.f;
    float a0v = 0.f, c0v = 0.f, a1v = 0.f, c1v = 0.f;
    if constexpr (STAGE >= 1) {
        bb1 = b1[chW];
        float mean = fstats[chW] * inv_cnt;
        float var  = fstats[64 + chW] * inv_cnt - mean * mean;
        a0v = g0[chW] * rsqrtf(fmaxf(var, 0.f) + BN_EPS);
        c0v = be0[chW] - a0v * mean;
    }
    if constexpr (STAGE == 2) {
        bb2a = b2[wv * 32 + ln];
        bb2b = b2[wv * 32 + 16 + ln];
        float mean = fstats[128 + chW] * inv_cnt;
        float var  = fstats[192 + chW] * inv_cnt - mean * mean;
        a1v = g1[chW] * rsqrtf(fmaxf(var, 0.f) + BN_EPS);
        c1v = be1[chW] - a1v * mean;
    }

    short8 zero8;
    zero8[0]=0;zero8[1]=0;zero8[2]=0;zero8[3]=0;
    zero8[4]=0;zero8[5]=0;zero8[6]=0;zero8[7]=0;

    constexpr int NT = (STAGE == 2) ? 2 : 1;
    float ssum[NT], ssq[NT];
#pragma unroll
    for (int nt = 0; nt < NT; ++nt) { ssum[nt] = 0.f; ssq[nt] = 0.f; }

    for (int tile = blockIdx.x; tile < ntiles; tile += gridDim.x) {
        const int m0 = tile * 2;       // 2 points = 64 samples per tile
        __syncthreads();               // prior tile's LDS reads done

        {   // ---- geometry staging only (waves 0,1), 64 samples ----
            const int s = t & 63;
            if (wv == 0) {             // unit8: [gx,gy,gz,rho,th,ph,nx,0]
                const int m = m0 + (s >> 5);
                const int j = gidx[m * NS + (s & 31)];
                float cjx, cjy, cjz, nx, cmx, cmy, cmz;
                if (cn) {
                    float4 cj = *(const float4*)(cn + (size_t)j * 8);
                    float4 cm = *(const float4*)(cn + (size_t)m * 8);
                    cjx=cj.x; cjy=cj.y; cjz=cj.z; nx=cj.w;
                    cmx=cm.x; cmy=cm.y; cmz=cm.z;
                } else {
                    cjx=center[j*3+0]; cjy=center[j*3+1]; cjz=center[j*3+2];
                    nx=normal[j*3+0];
                    cmx=center[m*3+0]; cmy=center[m*3+1]; cmz=center[m*3+2];
                }
                float gx = cjx - cmx, gy = cjy - cmy, gz = cjz - cmz;
                float rho = sqrtf(gx*gx + gy*gy + gz*gz);
                float th = 0.f;
                if (rho > 0.f) th = acosf(fminf(1.f, fmaxf(-1.f, gz / rho))) * INV_PI;
                float ph = atan2f(gy, gx) * INV_2PI + 0.5f;
                short8 v;
                v[0]=cvt_bf16(gx);  v[1]=cvt_bf16(gy); v[2]=cvt_bf16(gz);
                v[3]=cvt_bf16(rho); v[4]=cvt_bf16(th); v[5]=cvt_bf16(ph);
                v[6]=cvt_bf16(nx);  v[7]=0;
                *(short8*)(Xg + s * 20 + (s >> 4) * 4) = v;
            } else if (wv == 1) {      // unit9: [ny,nz,0,...]
                const int m = m0 + (s >> 5);
                const int j = gidx[m * NS + (s & 31)];
                float ny, nz;
                if (cn) {
                    float4 w = *(const float4*)(cn + (size_t)j * 8 + 4);
                    ny = w.x; nz = w.y;
                } else {
                    ny = normal[j*3+1]; nz = normal[j*3+2];
                }
                short8 v; v[0]=cvt_bf16(ny); v[1]=cvt_bf16(nz);
                v[2]=0;v[3]=0;v[4]=0;v[5]=0;v[6]=0;v[7]=0;
                *(short8*)(Xg + s * 20 + (s >> 4) * 4 + 8) = v;
            }
        }

        // per-lane neighbor index for own rows (row = mt*16+ln)
        int jv[4];
#pragma unroll
        for (int mt = 0; mt < 4; ++mt)
            jv[mt] = gidx[m0 * 32 + mt * 16 + ln];

        __syncthreads();               // Xg ready

        // ---- conv0: A direct from fb (kt 0,1) + Xg (kt 2, kg<2) ----
#pragma unroll
        for (int mt = 0; mt < 4; ++mt) {
            const int j = jv[mt];
            short8 A0, A1;
            if (fb) {
                A0 = *(const short8*)(fb + (size_t)j * 64 + kg * 8);
                A1 = *(const short8*)(fb + (size_t)j * 64 + 32 + kg * 8);
            } else {
                const float* fp = feature + (size_t)j * 64 + kg * 8;
#pragma unroll
                for (int q = 0; q < 8; ++q) {
                    A0[q] = cvt_bf16(fp[q]);
                    A1[q] = cvt_bf16(fp[32 + q]);
                }
            }
            short8 A2 = zero8;         // k 80..95: weights are zero
            if (kg < 2)
                A2 = *(const short8*)(Xg + (mt * 16 + ln) * 20 + mt * 4 + kg * 8);
            f32x4 acc = {bb0, bb0, bb0, bb0};
            acc = __builtin_amdgcn_mfma_f32_16x16x32_bf16(A0, W0[0], acc, 0, 0, 0);
            acc = __builtin_amdgcn_mfma_f32_16x16x32_bf16(A1, W0[1], acc, 0, 0, 0);
            acc = __builtin_amdgcn_mfma_f32_16x16x32_bf16(A2, W0[2], acc, 0, 0, 0);
            if constexpr (STAGE == 0) {
#pragma unroll
                for (int r = 0; r < 4; ++r) {
                    float y = acc[r];
                    ssum[0] += y; ssq[0] += y * y;
                }
            } else {
#pragma unroll
                for (int r = 0; r < 4; ++r) {
                    int row = mt * 16 + kg * 4 + r;
                    float x1 = fmaxf(a0v * acc[r] + c0v, 0.f);
                    X1s[row * 64 + ((((chW >> 3) ^ (row & 7)) << 3) | (chW & 7))] = cvt_bf16(x1);
                }
            }
        }
        if constexpr (STAGE >= 1) {
            __syncthreads();           // X1 complete
            // ---- conv1: K=64 ----
#pragma unroll 2
            for (int mt = 0; mt < 4; ++mt) {
                const short* arow = X1s + (mt * 16 + ln) * 64;
                f32x4 acc = {bb1, bb1, bb1, bb1};
#pragma unroll
                for (int kt = 0; kt < 2; ++kt) {
                    short8 A = *(const short8*)(arow + (((kt*4 + kg) ^ rs) * 8));
                    acc = __builtin_amdgcn_mfma_f32_16x16x32_bf16(A, W1[kt], acc, 0, 0, 0);
                }
                if constexpr (STAGE == 1) {
#pragma unroll
                    for (int r = 0; r < 4; ++r) {
                        float y = acc[r];
                        ssum[0] += y; ssq[0] += y * y;
                    }
                } else {
#pragma unroll
                    for (int r = 0; r < 4; ++r) {
                        int row = mt * 16 + kg * 4 + r;
                        float x2 = fmaxf(a1v * acc[r] + c1v, 0.f);
                        X2s[row * 64 + ((((chW >> 3) ^ (row & 7)) << 3) | (chW & 7))] = cvt_bf16(x2);
                    }
                }
            }
        }
        if constexpr (STAGE == 2) {
            __syncthreads();           // X2 complete
            // ---- conv2: wave's 32 cols, 2 points, stats + max/min ----
#pragma unroll
            for (int p = 0; p < 2; ++p) {
                float mx0 = -3.402823466e38f, mn0 = 3.402823466e38f;
                float mx1 = -3.402823466e38f, mn1 = 3.402823466e38f;
#pragma unroll
                for (int mh = 0; mh < 2; ++mh) {
                    const int mt = p * 2 + mh;
                    const short* arow = X2s + (mt * 16 + ln) * 64;
                    short8 A0 = *(const short8*)(arow + (((kg)     ^ rs) * 8));
                    short8 A1 = *(const short8*)(arow + (((4 + kg) ^ rs) * 8));
                    f32x4 acc = {bb2a, bb2a, bb2a, bb2a};
                    acc = __builtin_amdgcn_mfma_f32_16x16x32_bf16(A0, W2[0][0], acc, 0, 0, 0);
                    acc = __builtin_amdgcn_mfma_f32_16x16x32_bf16(A1, W2[0][1], acc, 0, 0, 0);
#pragma unroll
                    for (int r = 0; r < 4; ++r) {
                        float y = acc[r];
                        ssum[0] += y; ssq[0] += y * y;
                        mx0 = fmaxf(mx0, y); mn0 = fminf(mn0, y);
                    }
                    f32x4 acd = {bb2b, bb2b, bb2b, bb2b};
                    acd = __builtin_amdgcn_mfma_f32_16x16x32_bf16(A0, W2[1][0], acd, 0, 0, 0);
                    acd = __builtin_amdgcn_mfma_f32_16x16x32_bf16(A1, W2[1][1], acd, 0, 0, 0);
#pragma unroll
                    for (int r = 0; r < 4; ++r) {
                        float y = acd[r];
                        ssum[1] += y; ssq[1] += y * y;
                        mx1 = fmaxf(mx1, y); mn1 = fminf(mn1, y);
                    }
                }
                mx0 = fmaxf(mx0, __shfl_xor(mx0, 16)); mn0 = fminf(mn0, __shfl_xor(mn0, 16));
                mx0 = fmaxf(mx0, __shfl_xor(mx0, 32)); mn0 = fminf(mn0, __shfl_xor(mn0, 32));
                mx1 = fmaxf(mx1, __shfl_xor(mx1, 16)); mn1 = fminf(mn1, __shfl_xor(mn1, 16));
                mx1 = fmaxf(mx1, __shfl_xor(mx1, 32)); mn1 = fminf(mn1, __shfl_xor(mn1, 32));
                if (lane < 16) {
                    size_t base = (size_t)(m0 + p) * 128 + wv * 32 + ln;
                    ymax[base]      = mx0; ymin[base]      = mn0;
                    ymax[base + 16] = mx1; ymin[base + 16] = mn1;
                }
            }
        }
    }

    // ---- stats epilogue: channels disjoint per wave -> direct write ----
    float* pb = part + (size_t)blockIdx.x * 256;
#pragma unroll
    for (int nt = 0; nt < NT; ++nt) {
        float v = ssum[nt], q = ssq[nt];
        v += __shfl_xor(v, 16); q += __shfl_xor(q, 16);
        v += __shfl_xor(v, 32); q += __shfl_xor(q, 32);
        if (lane < 16) {
            constexpr int NCH = (STAGE == 2) ? 128 : 64;
            int c = (STAGE == 2) ? (wv * 32 + nt * 16 + ln) : (wv * 16 + ln);
            pb[c] = v; pb[NCH + c] = q;
        }
    }
}

__global__ __launch_bounds__(256) void reduce_partials(
    const float* __restrict__ part, float* __restrict__ fstats,
    int base, int nblocks)
{
    __shared__ float red[256];
    int c = blockIdx.x;
    float s = 0.f;
    for (int b = threadIdx.x; b < nblocks; b += 256)
        s += part[(size_t)b * 256 + c];
    red[threadIdx.x] = s;
    __syncthreads();
    for (int off = 128; off > 0; off >>= 1) {
        if (threadIdx.x < off) red[threadIdx.x] += red[threadIdx.x + off];
        __syncthreads();
    }
    if (threadIdx.x == 0) fstats[base + c] = red[0];
}

__global__ __launch_bounds__(256) void final_kernel(
    const float* __restrict__ center, const float* __restrict__ normal,
    const int* __restrict__ offs,
    const float* __restrict__ g2, const float* __restrict__ be2,
    const float* __restrict__ fstats,
    const float* __restrict__ ymax, const float* __restrict__ ymin,
    float* __restrict__ out, int N, float inv_cnt)
{
    int i = blockIdx.x * 256 + threadIdx.x;
    int nc = N * 3;
    int nf = N * 128;
    int total = 2 * nc + nf + 1;
    if (i >= total) return;
    if (i < nc) {
        out[i] = center[i];
    } else if (i < 2 * nc) {
        out[i] = normal[i - nc];
    } else if (i < 2 * nc + nf) {
        int idx = i - 2 * nc;
        int c = idx & 127;
        float mean = fstats[256 + c] * inv_cnt;
        float var  = fstats[384 + c] * inv_cnt - mean * mean;
        float a = g2[c] * rsqrtf(fmaxf(var, 0.f) + BN_EPS);
        float v = (a >= 0.f) ? ymax[idx] : ymin[idx];   // monotone BN+relu
        out[i] = fmaxf(a * (v - mean) + be2[c], 0.f);
    } else {
        out[i] = (float)offs[0];
    }
}

extern "C" void kernel_launch(void* const* d_in, const int* in_sizes, int n_in,
                              void* d_out, int out_size, void* d_ws, size_t ws_size,
                              hipStream_t stream)
{
    const float* center  = (const float*)d_in[0];
    const float* normal  = (const float*)d_in[1];
    const float* feature = (const float*)d_in[2];
    const int*   offs    = (const int*)d_in[3];
    const int*   gidx    = (const int*)d_in[4];
    const float* w0  = (const float*)d_in[5];
    const float* b0  = (const float*)d_in[6];
    const float* g0  = (const float*)d_in[7];
    const float* be0 = (const float*)d_in[8];
    const float* w1  = (const float*)d_in[9];
    const float* b1  = (const float*)d_in[10];
    const float* g1  = (const float*)d_in[11];
    const float* be1 = (const float*)d_in[12];
    const float* w2  = (const float*)d_in[13];
    const float* b2  = (const float*)d_in[14];
    const float* g2  = (const float*)d_in[15];
    const float* be2 = (const float*)d_in[16];

    const int N = in_sizes[0] / 3;
    const int ntiles = N / 2;          // 2 points per tile
    const float inv_cnt = 1.0f / (float)((size_t)N * NS);

    float* out = (float*)d_out;
    float* out_nf = out + (size_t)2 * N * 3;          // ymax in-place in d_out

    float* wsf    = (float*)d_ws;
    float* fstats = wsf;                              // [512]
    float* part   = wsf + 512;                        // [GRID01*256]
    float* ymin   = part + (size_t)GRID01 * 256;      // [N*128]
    short* wbase  = (short*)(ymin + (size_t)N * 128);
    short* wf0 = wbase;                // 12*512
    short* wf1 = wf0 + 12 * 512;       // 8*512
    short* wf2 = wf1 + 8 * 512;        // 16*512
    short* wend = wf2 + 16 * 512;

    // gather tables
    short* featbf = wend;                             // [N*64] bf16
    float* cn     = (float*)(featbf + (size_t)N * 64);// [N*8] fp32
    size_t need = (size_t)((char*)(cn + (size_t)N * 8) - (char*)d_ws);
    const bool has_tab = (ws_size >= need);
    const short* fbp = has_tab ? featbf : nullptr;
    const float* cnp = has_tab ? cn : nullptr;

    dim3 blk(256);

    prep_weights<<<dim3(9), blk, 0, stream>>>(w0, w1, w2, wf0, wf1, wf2);
    if (has_tab) {
        int n8 = N * 8;
        feat2bf<<<dim3((n8 + 255) / 256), blk, 0, stream>>>(feature, featbf, n8);
        prep_cn<<<dim3((N + 255) / 256), blk, 0, stream>>>(center, normal, cn, N);
    }

    stage_kernel<0><<<dim3(GRID01), blk, 0, stream>>>(center, normal, feature,
        fbp, cnp, gidx, wf0, wf1, wf2, b0, b1, b2,
        g0, be0, g1, be1, fstats, part, out_nf, ymin, ntiles, inv_cnt);
    reduce_partials<<<dim3(128), blk, 0, stream>>>(part, fstats, 0, GRID01);

    stage_kernel<1><<<dim3(GRID01), blk, 0, stream>>>(center, normal, feature,
        fbp, cnp, gidx, wf0, wf1, wf2, b0, b1, b2,
        g0, be0, g1, be1, fstats, part, out_nf, ymin, ntiles, inv_cnt);
    reduce_partials<<<dim3(128), blk, 0, stream>>>(part, fstats, 128, GRID01);

    stage_kernel<2><<<dim3(GRID2), blk, 0, stream>>>(center, normal, feature,
        fbp, cnp, gidx, wf0, wf1, wf2, b0, b1, b2,
        g0, be0, g1, be1, fstats, part, out_nf, ymin, ntiles, inv_cnt);
    reduce_partials<<<dim3(256), blk, 0, stream>>>(part, fstats, 256, GRID2);

    int total = 2 * N * 3 + N * 128 + 1;
    final_kernel<<<dim3((total + 255) / 256), blk, 0, stream>>>(
        center, normal, offs, g2, be2, fstats, out_nf, ymin, out, N, inv_cnt);
}

// Round 15
// 208.690 us; speedup vs baseline: 1.5866x; 1.5866x over previous
//
#include <hip/hip_runtime.h>
#include <hip/hip_bf16.h>
#include <math.h>

// SurfaceAbstraction: gather(32 nbrs) -> 73-dim -> 3x(1x1 conv + batch BN +
// relu) -> maxpool. BN stats => 3 recompute passes. R13 structure (best wall
// 225us): bf16 feature table + packed cn table (L2-resident gather), single
// bf16 weights, 2-point tiles, 5 blocks/CU (S0/S1) / 4 (S2).
// R15: prefetch ONLY the next tile's gidx value (1 VGPR) -- issued after this
// tile's LDS writes, consumed after the MFMA phase. Removes the first ~200cyc
// (gidx L2 hit) from every tile's post-barrier dependent chain. Full-row
// prefetch (R9/R10) and direct-from-table A-loads (R14) both failed; this is
// the minimal-footprint version of the same idea.

typedef __attribute__((ext_vector_type(8))) short short8;
typedef __attribute__((ext_vector_type(4))) float f32x4;

constexpr int NS = 32;
constexpr int GRIDS = 1280;    // 256 CU x 5 blocks
constexpr float BN_EPS = 1e-5f;
constexpr float INV_PI  = 0.31830988618379067f;
constexpr float INV_2PI = 0.15915494309189535f;

__device__ __forceinline__ short cvt_bf16(float f) {
    unsigned u = __float_as_uint(f);
    u = (u + 0x7FFFu + ((u >> 16) & 1u)) >> 16;
    return (short)u;
}

// feature (fp32) -> bf16 table
__global__ __launch_bounds__(256) void feat2bf(
    const float* __restrict__ feature, short* __restrict__ fb, int n8)
{
    int i = blockIdx.x * 256 + threadIdx.x;
    if (i >= n8) return;
    const float4* src = (const float4*)(feature + (size_t)i * 8);
    float4 a = src[0], b = src[1];
    short8 v;
    v[0]=cvt_bf16(a.x); v[1]=cvt_bf16(a.y); v[2]=cvt_bf16(a.z); v[3]=cvt_bf16(a.w);
    v[4]=cvt_bf16(b.x); v[5]=cvt_bf16(b.y); v[6]=cvt_bf16(b.z); v[7]=cvt_bf16(b.w);
    *(short8*)(fb + (size_t)i * 8) = v;
}

// packed per-point table: [cx,cy,cz,nx | ny,nz,0,0] fp32
__global__ __launch_bounds__(256) void prep_cn(
    const float* __restrict__ center, const float* __restrict__ normal,
    float* __restrict__ cn, int N)
{
    int i = blockIdx.x * 256 + threadIdx.x;
    if (i >= N) return;
    float4 a, b;
    a.x = center[i*3+0]; a.y = center[i*3+1]; a.z = center[i*3+2];
    a.w = normal[i*3+0];
    b.x = normal[i*3+1]; b.y = normal[i*3+2]; b.z = 0.f; b.w = 0.f;
    *(float4*)(cn + (size_t)i * 8)     = a;
    *(float4*)(cn + (size_t)i * 8 + 4) = b;
}

// Weight fragments: frag(kt,nt), lane l holds W[n=nt*16+(l&15)][k=kt*32+(l>>4)*8+j]
// single bf16. conv0 K map: kn<64 -> orig 9+kn (feat); 64..69 -> orig 0..5;
// 70 -> orig 6 (nx); 72 -> orig 7 (ny); 73 -> orig 8 (nz); 71, 74..95 -> 0.
__global__ __launch_bounds__(256) void prep_weights(
    const float* __restrict__ w0, const float* __restrict__ w1,
    const float* __restrict__ w2,
    short* __restrict__ wf0, short* __restrict__ wf1, short* __restrict__ wf2)
{
    int i = blockIdx.x * 256 + threadIdx.x;
    int l = i & 63;
    int f = i >> 6;
    float vals[8];
    short* dh;
    if (f < 12) {
        int kt = f >> 2, nt = f & 3;
        int n = nt * 16 + (l & 15);
        int k0 = kt * 32 + (l >> 4) * 8;
        for (int j = 0; j < 8; ++j) {
            int kn = k0 + j;
            float v;
            if (kn < 64)       v = w0[n * 73 + 9 + kn];
            else if (kn < 70)  v = w0[n * 73 + (kn - 64)];
            else if (kn == 70) v = w0[n * 73 + 6];
            else if (kn == 72) v = w0[n * 73 + 7];
            else if (kn == 73) v = w0[n * 73 + 8];
            else v = 0.f;
            vals[j] = v;
        }
        dh = wf0 + (size_t)f * 512 + l * 8;
    } else if (f < 20) {
        int ff = f - 12;
        int kt = ff >> 2, nt = ff & 3;
        int n = nt * 16 + (l & 15);
        int k0 = kt * 32 + (l >> 4) * 8;
        for (int j = 0; j < 8; ++j) vals[j] = w1[n * 64 + k0 + j];
        dh = wf1 + (size_t)ff * 512 + l * 8;
    } else if (f < 36) {
        int ff = f - 20;
        int kt = ff >> 3, nt = ff & 7;
        int n = nt * 16 + (l & 15);
        int k0 = kt * 32 + (l >> 4) * 8;
        for (int j = 0; j < 8; ++j) vals[j] = w2[n * 64 + k0 + j];
        dh = wf2 + (size_t)ff * 512 + l * 8;
    } else return;
    for (int j = 0; j < 8; ++j) dh[j] = cvt_bf16(vals[j]);
}

template <int STAGE>
__global__ __launch_bounds__(256, (STAGE == 2 ? 4 : 5)) void stage_kernel(
    const float* __restrict__ center, const float* __restrict__ normal,
    const float* __restrict__ feature, const short* __restrict__ fb,
    const float* __restrict__ cn, const int* __restrict__ gidx,
    const short* __restrict__ wf0, const short* __restrict__ wf1,
    const short* __restrict__ wf2,
    const float* __restrict__ b0, const float* __restrict__ b1,
    const float* __restrict__ b2,
    const float* __restrict__ g0, const float* __restrict__ be0,
    const float* __restrict__ g1, const float* __restrict__ be1,
    const float* __restrict__ fstats, float* __restrict__ part,
    float* __restrict__ ymax, float* __restrict__ ymin,
    int ntiles, float inv_cnt)
{
    // Xs: 64 rows x 16 units(16B), swizzle: unit u of row r at u^(r&7)
    __shared__ __align__(16) short Xs[64 * 128];
    __shared__ __align__(16) short X1s[(STAGE >= 1) ? 64 * 64 : 16];

    const int t    = threadIdx.x;
    const int lane = t & 63;
    const int wv   = __builtin_amdgcn_readfirstlane(t >> 6);
    const int ln   = lane & 15;
    const int kg   = lane >> 4;
    const int rs   = ln & 7;
    const int chW  = wv * 16 + ln;

    // ---- weight fragments in registers (single bf16) ----
    short8 W0[3];
#pragma unroll
    for (int kt = 0; kt < 3; ++kt)
        W0[kt] = *(const short8*)(wf0 + (size_t)((kt*4 + wv) * 64 + lane) * 8);
    short8 W1[2];
    if constexpr (STAGE >= 1) {
#pragma unroll
        for (int kt = 0; kt < 2; ++kt)
            W1[kt] = *(const short8*)(wf1 + (size_t)((kt*4 + wv) * 64 + lane) * 8);
    }
    short8 W2[2][2];
    if constexpr (STAGE == 2) {
#pragma unroll
        for (int nti = 0; nti < 2; ++nti)
#pragma unroll
            for (int kt = 0; kt < 2; ++kt) {
                int ff = kt * 8 + (wv * 2 + nti);
                W2[nti][kt] = *(const short8*)(wf2 + (size_t)(ff * 64 + lane) * 8);
            }
    }

    // ---- biases / BN consts (per-lane; channel fixed) ----
    const float bb0 = b0[chW];
    float bb1 = 0.f, bb2a = 0.f, bb2b = 0.f;
    float a0v = 0.f, c0v = 0.f, a1v = 0.f, c1v = 0.f;
    if constexpr (STAGE >= 1) {
        bb1 = b1[chW];
        float mean = fstats[chW] * inv_cnt;
        float var  = fstats[64 + chW] * inv_cnt - mean * mean;
        a0v = g0[chW] * rsqrtf(fmaxf(var, 0.f) + BN_EPS);
        c0v = be0[chW] - a0v * mean;
    }
    if constexpr (STAGE == 2) {
        bb2a = b2[wv * 32 + ln];
        bb2b = b2[wv * 32 + 16 + ln];
        float mean = fstats[128 + chW] * inv_cnt;
        float var  = fstats[192 + chW] * inv_cnt - mean * mean;
        a1v = g1[chW] * rsqrtf(fmaxf(var, 0.f) + BN_EPS);
        c1v = be1[chW] - a1v * mean;
    }

    if (t < 128) {  // zero pad units 10,11 (k 80..95) once; never overwritten
        int r = t >> 1, u = 10 + (t & 1);
        short8 z; z[0]=0;z[1]=0;z[2]=0;z[3]=0;z[4]=0;z[5]=0;z[6]=0;z[7]=0;
        *(short8*)(Xs + r * 128 + ((u ^ (r & 7)) * 8)) = z;
    }

    constexpr int NT = (STAGE == 2) ? 2 : 1;
    float ssum[NT], ssq[NT];
#pragma unroll
    for (int nt = 0; nt < NT; ++nt) { ssum[nt] = 0.f; ssq[nt] = 0.f; }

    // ---- gidx prefetch (1 VGPR): break the gidx->table dependent chain ----
    const int s  = t & 63;
    const int sm = s >> 5;
    const int sj = s & 31;
    int jpf = 0;
    if ((int)blockIdx.x < ntiles)
        jpf = gidx[(blockIdx.x * 2 + sm) * NS + sj];

    for (int tile = blockIdx.x; tile < ntiles; tile += gridDim.x) {
        const int m0 = tile * 2;       // 2 points = 64 samples per tile
        __syncthreads();               // prior tile's LDS reads done
        {   // ---- gather: 64 samples, 4 threads/sample (h = wave id) ----
            const int h = wv;
            const int m = m0 + sm;
            const int j = jpf;         // prefetched last iteration
            short* xr = Xs + s * 128;
            const int rx = s & 7;
            if (fb) {                  // bf16 table: pure 16B copies
                const uint4* fp = (const uint4*)(fb + (size_t)j * 64);
                uint4 v0 = fp[2 * h], v1 = fp[2 * h + 1];
                *(uint4*)(xr + (((2 * h)     ^ rx) * 8)) = v0;
                *(uint4*)(xr + (((2 * h + 1) ^ rx) * 8)) = v1;
            } else {
                const float4* fp = (const float4*)(feature + (size_t)j * 64 + h * 16);
#pragma unroll
                for (int q = 0; q < 2; ++q) {
                    float4 a = fp[2 * q], b = fp[2 * q + 1];
                    short8 v;
                    v[0]=cvt_bf16(a.x); v[1]=cvt_bf16(a.y); v[2]=cvt_bf16(a.z); v[3]=cvt_bf16(a.w);
                    v[4]=cvt_bf16(b.x); v[5]=cvt_bf16(b.y); v[6]=cvt_bf16(b.z); v[7]=cvt_bf16(b.w);
                    *(short8*)(xr + (((2 * h + q) ^ rx) * 8)) = v;
                }
            }
            if (h == 0) {              // unit 8: [gx,gy,gz,rho,th,ph,nx,0]
                float cjx, cjy, cjz, nx, cmx, cmy, cmz;
                if (cn) {
                    float4 cj = *(const float4*)(cn + (size_t)j * 8);
                    float4 cm = *(const float4*)(cn + (size_t)m * 8);
                    cjx=cj.x; cjy=cj.y; cjz=cj.z; nx=cj.w;
                    cmx=cm.x; cmy=cm.y; cmz=cm.z;
                } else {
                    cjx=center[j*3+0]; cjy=center[j*3+1]; cjz=center[j*3+2];
                    nx=normal[j*3+0];
                    cmx=center[m*3+0]; cmy=center[m*3+1]; cmz=center[m*3+2];
                }
                float gx = cjx - cmx, gy = cjy - cmy, gz = cjz - cmz;
                float rho = sqrtf(gx*gx + gy*gy + gz*gz);
                float th = 0.f;
                if (rho > 0.f) th = acosf(fminf(1.f, fmaxf(-1.f, gz / rho))) * INV_PI;
                float ph = atan2f(gy, gx) * INV_2PI + 0.5f;
                short8 v;
                v[0]=cvt_bf16(gx);  v[1]=cvt_bf16(gy); v[2]=cvt_bf16(gz);
                v[3]=cvt_bf16(rho); v[4]=cvt_bf16(th); v[5]=cvt_bf16(ph);
                v[6]=cvt_bf16(nx);  v[7]=0;
                *(short8*)(xr + ((8 ^ rx) * 8)) = v;
            } else if (h == 1) {       // unit 9: [ny,nz,0,...]
                float ny, nz;
                if (cn) {
                    float4 w = *(const float4*)(cn + (size_t)j * 8 + 4);
                    ny = w.x; nz = w.y;
                } else {
                    ny = normal[j*3+1]; nz = normal[j*3+2];
                }
                short8 v; v[0]=cvt_bf16(ny); v[1]=cvt_bf16(nz);
                v[2]=0;v[3]=0;v[4]=0;v[5]=0;v[6]=0;v[7]=0;
                *(short8*)(xr + ((9 ^ rx) * 8)) = v;
            }
        }
        {   // prefetch next tile's gidx (flies under the MFMA phase;
            // __syncthreads below is a memory fence, compiler can't sink it)
            int nxt = tile + gridDim.x;
            if (nxt < ntiles)
                jpf = gidx[(nxt * 2 + sm) * NS + sj];
        }
        __syncthreads();
        // ---- conv0: wave's 16 cols x 4 m-tiles, K=96 ----
#pragma unroll 2
        for (int mt = 0; mt < 4; ++mt) {
            const short* arow = Xs + (mt * 16 + ln) * 128;
            f32x4 acc = {bb0, bb0, bb0, bb0};
#pragma unroll
            for (int kt = 0; kt < 3; ++kt) {
                short8 A = *(const short8*)(arow + (((kt*4 + kg) ^ rs) * 8));
                acc = __builtin_amdgcn_mfma_f32_16x16x32_bf16(A, W0[kt], acc, 0, 0, 0);
            }
            if constexpr (STAGE == 0) {
#pragma unroll
                for (int r = 0; r < 4; ++r) {
                    float y = acc[r];
                    ssum[0] += y; ssq[0] += y * y;
                }
            } else {
#pragma unroll
                for (int r = 0; r < 4; ++r) {
                    int row = mt * 16 + kg * 4 + r;
                    float x1 = fmaxf(a0v * acc[r] + c0v, 0.f);
                    X1s[row * 64 + ((((chW >> 3) ^ (row & 7)) << 3) | (chW & 7))] = cvt_bf16(x1);
                }
            }
        }
        if constexpr (STAGE >= 1) {
            __syncthreads();           // X1 complete
            // ---- conv1: K=64 ----
#pragma unroll 2
            for (int mt = 0; mt < 4; ++mt) {
                const short* arow = X1s + (mt * 16 + ln) * 64;
                f32x4 acc = {bb1, bb1, bb1, bb1};
#pragma unroll
                for (int kt = 0; kt < 2; ++kt) {
                    short8 A = *(const short8*)(arow + (((kt*4 + kg) ^ rs) * 8));
                    acc = __builtin_amdgcn_mfma_f32_16x16x32_bf16(A, W1[kt], acc, 0, 0, 0);
                }
                if constexpr (STAGE == 1) {
#pragma unroll
                    for (int r = 0; r < 4; ++r) {
                        float y = acc[r];
                        ssum[0] += y; ssq[0] += y * y;
                    }
                } else {
#pragma unroll
                    for (int r = 0; r < 4; ++r) {
                        int row = mt * 16 + kg * 4 + r;
                        float x2 = fmaxf(a1v * acc[r] + c1v, 0.f);
                        Xs[row * 128 + ((((chW >> 3) ^ (row & 7)) << 3) | (chW & 7))] = cvt_bf16(x2);
                    }
                }
            }
        }
        if constexpr (STAGE == 2) {
            __syncthreads();           // X2 complete (Xs units 0..7)
            // ---- conv2: wave's 32 cols, 2 points, stats + max/min ----
#pragma unroll
            for (int p = 0; p < 2; ++p) {
                float mx0 = -3.402823466e38f, mn0 = 3.402823466e38f;
                float mx1 = -3.402823466e38f, mn1 = 3.402823466e38f;
#pragma unroll
                for (int mh = 0; mh < 2; ++mh) {
                    const int mt = p * 2 + mh;
                    const short* arow = Xs + (mt * 16 + ln) * 128;
                    short8 A0 = *(const short8*)(arow + (((kg)     ^ rs) * 8));
                    short8 A1 = *(const short8*)(arow + (((4 + kg) ^ rs) * 8));
                    f32x4 acc = {bb2a, bb2a, bb2a, bb2a};
                    acc = __builtin_amdgcn_mfma_f32_16x16x32_bf16(A0, W2[0][0], acc, 0, 0, 0);
                    acc = __builtin_amdgcn_mfma_f32_16x16x32_bf16(A1, W2[0][1], acc, 0, 0, 0);
#pragma unroll
                    for (int r = 0; r < 4; ++r) {
                        float y = acc[r];
                        ssum[0] += y; ssq[0] += y * y;
                        mx0 = fmaxf(mx0, y); mn0 = fminf(mn0, y);
                    }
                    f32x4 acd = {bb2b, bb2b, bb2b, bb2b};
                    acd = __builtin_amdgcn_mfma_f32_16x16x32_bf16(A0, W2[1][0], acd, 0, 0, 0);
                    acd = __builtin_amdgcn_mfma_f32_16x16x32_bf16(A1, W2[1][1], acd, 0, 0, 0);
#pragma unroll
                    for (int r = 0; r < 4; ++r) {
                        float y = acd[r];
                        ssum[1] += y; ssq[1] += y * y;
                        mx1 = fmaxf(mx1, y); mn1 = fminf(mn1, y);
                    }
                }
                mx0 = fmaxf(mx0, __shfl_xor(mx0, 16)); mn0 = fminf(mn0, __shfl_xor(mn0, 16));
                mx0 = fmaxf(mx0, __shfl_xor(mx0, 32)); mn0 = fminf(mn0, __shfl_xor(mn0, 32));
                mx1 = fmaxf(mx1, __shfl_xor(mx1, 16)); mn1 = fminf(mn1, __shfl_xor(mn1, 16));
                mx1 = fmaxf(mx1, __shfl_xor(mx1, 32)); mn1 = fminf(mn1, __shfl_xor(mn1, 32));
                if (lane < 16) {
                    size_t base = (size_t)(m0 + p) * 128 + wv * 32 + ln;
                    ymax[base]      = mx0; ymin[base]      = mn0;
                    ymax[base + 16] = mx1; ymin[base + 16] = mn1;
                }
            }
        }
    }

    // ---- stats epilogue: channels disjoint per wave -> direct write ----
    float* pb = part + (size_t)blockIdx.x * 256;
#pragma unroll
    for (int nt = 0; nt < NT; ++nt) {
        float v = ssum[nt], q = ssq[nt];
        v += __shfl_xor(v, 16); q += __shfl_xor(q, 16);
        v += __shfl_xor(v, 32); q += __shfl_xor(q, 32);
        if (lane < 16) {
            constexpr int NCH = (STAGE == 2) ? 128 : 64;
            int c = (STAGE == 2) ? (wv * 32 + nt * 16 + ln) : (wv * 16 + ln);
            pb[c] = v; pb[NCH + c] = q;
        }
    }
}

__global__ __launch_bounds__(256) void reduce_partials(
    const float* __restrict__ part, float* __restrict__ fstats,
    int base, int nblocks)
{
    __shared__ float red[256];
    int c = blockIdx.x;
    float s = 0.f;
    for (int b = threadIdx.x; b < nblocks; b += 256)
        s += part[(size_t)b * 256 + c];
    red[threadIdx.x] = s;
    __syncthreads();
    for (int off = 128; off > 0; off >>= 1) {
        if (threadIdx.x < off) red[threadIdx.x] += red[threadIdx.x + off];
        __syncthreads();
    }
    if (threadIdx.x == 0) fstats[base + c] = red[0];
}

__global__ __launch_bounds__(256) void final_kernel(
    const float* __restrict__ center, const float* __restrict__ normal,
    const int* __restrict__ offs,
    const float* __restrict__ g2, const float* __restrict__ be2,
    const float* __restrict__ fstats,
    const float* __restrict__ ymax, const float* __restrict__ ymin,
    float* __restrict__ out, int N, float inv_cnt)
{
    int i = blockIdx.x * 256 + threadIdx.x;
    int nc = N * 3;
    int nf = N * 128;
    int total = 2 * nc + nf + 1;
    if (i >= total) return;
    if (i < nc) {
        out[i] = center[i];
    } else if (i < 2 * nc) {
        out[i] = normal[i - nc];
    } else if (i < 2 * nc + nf) {
        int idx = i - 2 * nc;
        int c = idx & 127;
        float mean = fstats[256 + c] * inv_cnt;
        float var  = fstats[384 + c] * inv_cnt - mean * mean;
        float a = g2[c] * rsqrtf(fmaxf(var, 0.f) + BN_EPS);
        float v = (a >= 0.f) ? ymax[idx] : ymin[idx];   // monotone BN+relu
        out[i] = fmaxf(a * (v - mean) + be2[c], 0.f);
    } else {
        out[i] = (float)offs[0];
    }
}

extern "C" void kernel_launch(void* const* d_in, const int* in_sizes, int n_in,
                              void* d_out, int out_size, void* d_ws, size_t ws_size,
                              hipStream_t stream)
{
    const float* center  = (const float*)d_in[0];
    const float* normal  = (const float*)d_in[1];
    const float* feature = (const float*)d_in[2];
    const int*   offs    = (const int*)d_in[3];
    const int*   gidx    = (const int*)d_in[4];
    const float* w0  = (const float*)d_in[5];
    const float* b0  = (const float*)d_in[6];
    const float* g0  = (const float*)d_in[7];
    const float* be0 = (const float*)d_in[8];
    const float* w1  = (const float*)d_in[9];
    const float* b1  = (const float*)d_in[10];
    const float* g1  = (const float*)d_in[11];
    const float* be1 = (const float*)d_in[12];
    const float* w2  = (const float*)d_in[13];
    const float* b2  = (const float*)d_in[14];
    const float* g2  = (const float*)d_in[15];
    const float* be2 = (const float*)d_in[16];

    const int N = in_sizes[0] / 3;
    const int ntiles = N / 2;          // 2 points per tile
    const float inv_cnt = 1.0f / (float)((size_t)N * NS);

    float* out = (float*)d_out;
    float* out_nf = out + (size_t)2 * N * 3;          // ymax in-place in d_out

    float* wsf    = (float*)d_ws;
    float* fstats = wsf;                              // [512]
    float* part   = wsf + 512;                        // [GRIDS*256]
    float* ymin   = part + (size_t)GRIDS * 256;       // [N*128]
    short* wbase  = (short*)(ymin + (size_t)N * 128);
    short* wf0 = wbase;                // 12*512
    short* wf1 = wf0 + 12 * 512;       // 8*512
    short* wf2 = wf1 + 8 * 512;        // 16*512
    short* wend = wf2 + 16 * 512;

    // gather tables
    short* featbf = wend;                             // [N*64] bf16
    float* cn     = (float*)(featbf + (size_t)N * 64);// [N*8] fp32
    size_t need = (size_t)((char*)(cn + (size_t)N * 8) - (char*)d_ws);
    const bool has_tab = (ws_size >= need);
    const short* fbp = has_tab ? featbf : nullptr;
    const float* cnp = has_tab ? cn : nullptr;

    dim3 blk(256);

    prep_weights<<<dim3(9), blk, 0, stream>>>(w0, w1, w2, wf0, wf1, wf2);
    if (has_tab) {
        int n8 = N * 8;
        feat2bf<<<dim3((n8 + 255) / 256), blk, 0, stream>>>(feature, featbf, n8);
        prep_cn<<<dim3((N + 255) / 256), blk, 0, stream>>>(center, normal, cn, N);
    }

    stage_kernel<0><<<dim3(GRIDS), blk, 0, stream>>>(center, normal, feature,
        fbp, cnp, gidx, wf0, wf1, wf2, b0, b1, b2,
        g0, be0, g1, be1, fstats, part, out_nf, ymin, ntiles, inv_cnt);
    reduce_partials<<<dim3(128), blk, 0, stream>>>(part, fstats, 0, GRIDS);

    stage_kernel<1><<<dim3(GRIDS), blk, 0, stream>>>(center, normal, feature,
        fbp, cnp, gidx, wf0, wf1, wf2, b0, b1, b2,
        g0, be0, g1, be1, fstats, part, out_nf, ymin, ntiles, inv_cnt);
    reduce_partials<<<dim3(128), blk, 0, stream>>>(part, fstats, 128, GRIDS);

    stage_kernel<2><<<dim3(GRIDS), blk, 0, stream>>>(center, normal, feature,
        fbp, cnp, gidx, wf0, wf1, wf2, b0, b1, b2,
        g0, be0, g1, be1, fstats, part, out_nf, ymin, ntiles, inv_cnt);
    reduce_partials<<<dim3(256), blk, 0, stream>>>(part, fstats, 256, GRIDS);

    int total = 2 * N * 3 + N * 128 + 1;
    final_kernel<<<dim3((total + 255) / 256), blk, 0, stream>>>(
        center, normal, offs, g2, be2, fstats, out_nf, ymin, out, N, inv_cnt);
}

// Round 16
// 192.324 us; speedup vs baseline: 1.7216x; 1.0851x over previous
//
#include <hip/hip_runtime.h>
#include <hip/hip_bf16.h>
#include <math.h>

// SurfaceAbstraction: gather(32 nbrs) -> 73-dim -> 3x(1x1 conv + batch BN +
// relu) -> maxpool. BN stats => 3 recompute passes. bf16 feature table +
// packed cn table (L2-resident), single-bf16 weights, gidx prefetch (R15).
// R16: ASYNC fb staging via global_load_lds (no VGPR staging => no spill):
//  - Xs split: XsF[64 rows x 8 granules(16B)] granule-linear (slot=u^(row&7),
//    u<8 <=> slot<8 so fb fills slots 0..7 = "uniform base + lane*16" shape),
//    DOUBLE-buffered; XsG[64 x 48B] geometry (2-way free, no swizzle).
//  - loop: B0 drains fb(t) (issued a compute-phase ago); A: geometry(t)->XsG
//    + load next-tile j's; B1 (drains j's); issue fb(t+1)->XsF[nxt] (2x
//    gload_lds per wave, per-lane pre-swizzled src); compute(t) from XsF[cur].
//  Loop-carried staging: jg only (1 int). Occupancy 6/5/4 blocks/CU.

typedef __attribute__((ext_vector_type(8))) short short8;
typedef __attribute__((ext_vector_type(4))) float f32x4;

constexpr int NS = 32;
constexpr int GRID_S0 = 1536;  // 6 blocks/CU
constexpr int GRID_S1 = 1280;  // 5
constexpr int GRID_S2 = 1024;  // 4
constexpr int GRID_MAX = 1536;
constexpr float BN_EPS = 1e-5f;
constexpr float INV_PI  = 0.31830988618379067f;
constexpr float INV_2PI = 0.15915494309189535f;

__device__ __forceinline__ short cvt_bf16(float f) {
    unsigned u = __float_as_uint(f);
    u = (u + 0x7FFFu + ((u >> 16) & 1u)) >> 16;
    return (short)u;
}

__device__ __forceinline__ void gload_lds16(const short* src, short* dst_lds) {
    __builtin_amdgcn_global_load_lds(
        (const __attribute__((address_space(1))) unsigned int*)src,
        (__attribute__((address_space(3))) unsigned int*)dst_lds, 16, 0, 0);
}

// feature (fp32) -> bf16 table
__global__ __launch_bounds__(256) void feat2bf(
    const float* __restrict__ feature, short* __restrict__ fb, int n8)
{
    int i = blockIdx.x * 256 + threadIdx.x;
    if (i >= n8) return;
    const float4* src = (const float4*)(feature + (size_t)i * 8);
    float4 a = src[0], b = src[1];
    short8 v;
    v[0]=cvt_bf16(a.x); v[1]=cvt_bf16(a.y); v[2]=cvt_bf16(a.z); v[3]=cvt_bf16(a.w);
    v[4]=cvt_bf16(b.x); v[5]=cvt_bf16(b.y); v[6]=cvt_bf16(b.z); v[7]=cvt_bf16(b.w);
    *(short8*)(fb + (size_t)i * 8) = v;
}

// packed per-point table: [cx,cy,cz,nx | ny,nz,0,0] fp32
__global__ __launch_bounds__(256) void prep_cn(
    const float* __restrict__ center, const float* __restrict__ normal,
    float* __restrict__ cn, int N)
{
    int i = blockIdx.x * 256 + threadIdx.x;
    if (i >= N) return;
    float4 a, b;
    a.x = center[i*3+0]; a.y = center[i*3+1]; a.z = center[i*3+2];
    a.w = normal[i*3+0];
    b.x = normal[i*3+1]; b.y = normal[i*3+2]; b.z = 0.f; b.w = 0.f;
    *(float4*)(cn + (size_t)i * 8)     = a;
    *(float4*)(cn + (size_t)i * 8 + 4) = b;
}

// Weight fragments: frag(kt,nt), lane l holds W[n=nt*16+(l&15)][k=kt*32+(l>>4)*8+j]
// single bf16. conv0 K map: kn<64 -> orig 9+kn (feat); 64..69 -> orig 0..5;
// 70 -> orig 6 (nx); 72 -> orig 7 (ny); 73 -> orig 8 (nz); 71, 74..95 -> 0.
__global__ __launch_bounds__(256) void prep_weights(
    const float* __restrict__ w0, const float* __restrict__ w1,
    const float* __restrict__ w2,
    short* __restrict__ wf0, short* __restrict__ wf1, short* __restrict__ wf2)
{
    int i = blockIdx.x * 256 + threadIdx.x;
    int l = i & 63;
    int f = i >> 6;
    float vals[8];
    short* dh;
    if (f < 12) {
        int kt = f >> 2, nt = f & 3;
        int n = nt * 16 + (l & 15);
        int k0 = kt * 32 + (l >> 4) * 8;
        for (int j = 0; j < 8; ++j) {
            int kn = k0 + j;
            float v;
            if (kn < 64)       v = w0[n * 73 + 9 + kn];
            else if (kn < 70)  v = w0[n * 73 + (kn - 64)];
            else if (kn == 70) v = w0[n * 73 + 6];
            else if (kn == 72) v = w0[n * 73 + 7];
            else if (kn == 73) v = w0[n * 73 + 8];
            else v = 0.f;
            vals[j] = v;
        }
        dh = wf0 + (size_t)f * 512 + l * 8;
    } else if (f < 20) {
        int ff = f - 12;
        int kt = ff >> 2, nt = ff & 3;
        int n = nt * 16 + (l & 15);
        int k0 = kt * 32 + (l >> 4) * 8;
        for (int j = 0; j < 8; ++j) vals[j] = w1[n * 64 + k0 + j];
        dh = wf1 + (size_t)ff * 512 + l * 8;
    } else if (f < 36) {
        int ff = f - 20;
        int kt = ff >> 3, nt = ff & 7;
        int n = nt * 16 + (l & 15);
        int k0 = kt * 32 + (l >> 4) * 8;
        for (int j = 0; j < 8; ++j) vals[j] = w2[n * 64 + k0 + j];
        dh = wf2 + (size_t)ff * 512 + l * 8;
    } else return;
    for (int j = 0; j < 8; ++j) dh[j] = cvt_bf16(vals[j]);
}

template <int STAGE, bool PIPE>
__global__ __launch_bounds__(256, (STAGE == 0 ? 6 : (STAGE == 1 ? 5 : 4)))
void stage_kernel(
    const float* __restrict__ center, const float* __restrict__ normal,
    const float* __restrict__ feature, const short* __restrict__ fb,
    const float* __restrict__ cn, const int* __restrict__ gidx,
    const short* __restrict__ wf0, const short* __restrict__ wf1,
    const short* __restrict__ wf2,
    const float* __restrict__ b0, const float* __restrict__ b1,
    const float* __restrict__ b2,
    const float* __restrict__ g0, const float* __restrict__ be0,
    const float* __restrict__ g1, const float* __restrict__ be1,
    const float* __restrict__ fstats, float* __restrict__ part,
    float* __restrict__ ymax, float* __restrict__ ymin,
    int ntiles, float inv_cnt)
{
    // XsF: feature K 0..63; granule g=row*8+slot (16B), content u = slot^(row&7)
    __shared__ __align__(16) short XsF[PIPE ? 2 * 64 * 64 : 64 * 64];
    __shared__ __align__(16) short XsG[64 * 24];   // units 8,9 @ 48B rows
    __shared__ __align__(16) short X1s[(STAGE >= 1) ? 64 * 64 : 16];
    __shared__ __align__(16) short X2s[(STAGE == 2) ? 64 * 64 : 16];

    const int t    = threadIdx.x;
    const int lane = t & 63;
    const int wv   = __builtin_amdgcn_readfirstlane(t >> 6);
    const int ln   = lane & 15;
    const int kg   = lane >> 4;
    const int rs   = ln & 7;
    const int chW  = wv * 16 + ln;

    // ---- weight fragments in registers ----
    short8 W0[3];
#pragma unroll
    for (int kt = 0; kt < 3; ++kt)
        W0[kt] = *(const short8*)(wf0 + (size_t)((kt*4 + wv) * 64 + lane) * 8);
    short8 W1[2];
    if constexpr (STAGE >= 1) {
#pragma unroll
        for (int kt = 0; kt < 2; ++kt)
            W1[kt] = *(const short8*)(wf1 + (size_t)((kt*4 + wv) * 64 + lane) * 8);
    }
    short8 W2[2][2];
    if constexpr (STAGE == 2) {
#pragma unroll
        for (int nti = 0; nti < 2; ++nti)
#pragma unroll
            for (int kt = 0; kt < 2; ++kt) {
                int ff = kt * 8 + (wv * 2 + nti);
                W2[nti][kt] = *(const short8*)(wf2 + (size_t)(ff * 64 + lane) * 8);
            }
    }

    // ---- biases / BN consts ----
    const float bb0 = b0[chW];
    float bb1 = 0.f, bb2a = 0.f, bb2b = 0.f;
    float a0v = 0.f, c0v = 0.f, a1v = 0.f, c1v = 0.f;
    if constexpr (STAGE >= 1) {
        bb1 = b1[chW];
        float mean = fstats[chW] * inv_cnt;
        float var  = fstats[64 + chW] * inv_cnt - mean * mean;
        a0v = g0[chW] * rsqrtf(fmaxf(var, 0.f) + BN_EPS);
        c0v = be0[chW] - a0v * mean;
    }
    if constexpr (STAGE == 2) {
        bb2a = b2[wv * 32 + ln];
        bb2b = b2[wv * 32 + 16 + ln];
        float mean = fstats[128 + chW] * inv_cnt;
        float var  = fstats[192 + chW] * inv_cnt - mean * mean;
        a1v = g1[chW] * rsqrtf(fmaxf(var, 0.f) + BN_EPS);
        c1v = be1[chW] - a1v * mean;
    }

    short8 zero8;
    zero8[0]=0;zero8[1]=0;zero8[2]=0;zero8[3]=0;
    zero8[4]=0;zero8[5]=0;zero8[6]=0;zero8[7]=0;

    constexpr int NT = (STAGE == 2) ? 2 : 1;
    float ssum[NT], ssq[NT];
#pragma unroll
    for (int nt = 0; nt < NT; ++nt) { ssum[nt] = 0.f; ssq[nt] = 0.f; }

    // ---- gather lane mappings ----
    const int s  = t & 63;                 // geometry sample
    const int sm = s >> 5;
    const int sj = s & 31;
    const int rowA = (wv * 2 + 0) * 8 + (lane >> 3);   // fb issue rows
    const int rowB = (wv * 2 + 1) * 8 + (lane >> 3);
    // per-lane swizzled unit for fb issues
    const int gA = (wv * 2 + 0) * 64 + lane;
    const int gB = (wv * 2 + 1) * 64 + lane;
    const int uA = (gA & 7) ^ (rowA & 7);
    const int uB = (gB & 7) ^ (rowB & 7);

    int cur = 0;
    int jg = 0;
    {   // ---- prologue: j's for tile0 + issue fb(tile0) -> XsF[0] ----
        int t0 = blockIdx.x;
        if (t0 < ntiles) {
            jg = gidx[(t0 * 2 + sm) * NS + sj];
            if constexpr (PIPE) {
                int ja = gidx[(t0 * 2 + (rowA >> 5)) * NS + (rowA & 31)];
                int jb = gidx[(t0 * 2 + (rowB >> 5)) * NS + (rowB & 31)];
                gload_lds16(fb + (size_t)ja * 64 + uA * 8,
                            XsF + (wv * 2 + 0) * 512);
                gload_lds16(fb + (size_t)jb * 64 + uB * 8,
                            XsF + (wv * 2 + 1) * 512);
            }
        }
    }

    for (int tile = blockIdx.x; tile < ntiles; tile += gridDim.x) {
        const int m0 = tile * 2;
        __syncthreads();               // B0: fb(t)->XsF[cur] drained; compute(t-1) done
        short* XsFc = XsF + (PIPE ? cur * 4096 : 0);
        short* XsFn = XsF + (PIPE ? (cur ^ 1) * 4096 : 0);

        {   // ---- A: geometry(t) -> XsG; (fallback: fb copy too) ----
            const int m = m0 + sm;
            const int j = jg;          // prefetched
            if constexpr (!PIPE) {     // sync fb/feature copy, 4 thr/sample
                short* xr = XsFc + s * 64;
                const int rx = s & 7;
                if (fb) {
                    const uint4* fp = (const uint4*)(fb + (size_t)j * 64);
                    uint4 v0 = fp[2 * wv], v1 = fp[2 * wv + 1];
                    *(uint4*)(xr + (((2 * wv)     ^ rx) * 8)) = v0;
                    *(uint4*)(xr + (((2 * wv + 1) ^ rx) * 8)) = v1;
                } else {
                    const float4* fp = (const float4*)(feature + (size_t)j * 64 + wv * 16);
#pragma unroll
                    for (int q = 0; q < 2; ++q) {
                        float4 a = fp[2 * q], b = fp[2 * q + 1];
                        short8 v;
                        v[0]=cvt_bf16(a.x); v[1]=cvt_bf16(a.y); v[2]=cvt_bf16(a.z); v[3]=cvt_bf16(a.w);
                        v[4]=cvt_bf16(b.x); v[5]=cvt_bf16(b.y); v[6]=cvt_bf16(b.z); v[7]=cvt_bf16(b.w);
                        *(short8*)(xr + (((2 * wv + q) ^ rx) * 8)) = v;
                    }
                }
            }
            if (wv == 0) {             // unit 8: [gx,gy,gz,rho,th,ph,nx,0]
                float cjx, cjy, cjz, nx, cmx, cmy, cmz;
                if (cn) {
                    float4 cj = *(const float4*)(cn + (size_t)j * 8);
                    float4 cm = *(const float4*)(cn + (size_t)m * 8);
                    cjx=cj.x; cjy=cj.y; cjz=cj.z; nx=cj.w;
                    cmx=cm.x; cmy=cm.y; cmz=cm.z;
                } else {
                    cjx=center[j*3+0]; cjy=center[j*3+1]; cjz=center[j*3+2];
                    nx=normal[j*3+0];
                    cmx=center[m*3+0]; cmy=center[m*3+1]; cmz=center[m*3+2];
                }
                float gx = cjx - cmx, gy = cjy - cmy, gz = cjz - cmz;
                float rho = sqrtf(gx*gx + gy*gy + gz*gz);
                float th = 0.f;
                if (rho > 0.f) th = acosf(fminf(1.f, fmaxf(-1.f, gz / rho))) * INV_PI;
                float ph = atan2f(gy, gx) * INV_2PI + 0.5f;
                short8 v;
                v[0]=cvt_bf16(gx);  v[1]=cvt_bf16(gy); v[2]=cvt_bf16(gz);
                v[3]=cvt_bf16(rho); v[4]=cvt_bf16(th); v[5]=cvt_bf16(ph);
                v[6]=cvt_bf16(nx);  v[7]=0;
                *(short8*)(XsG + s * 24) = v;
            } else if (wv == 1) {      // unit 9: [ny,nz,0,...]
                float ny, nz;
                if (cn) {
                    float4 w = *(const float4*)(cn + (size_t)j * 8 + 4);
                    ny = w.x; nz = w.y;
                } else {
                    ny = normal[j*3+1]; nz = normal[j*3+2];
                }
                short8 v; v[0]=cvt_bf16(ny); v[1]=cvt_bf16(nz);
                v[2]=0;v[3]=0;v[4]=0;v[5]=0;v[6]=0;v[7]=0;
                *(short8*)(XsG + s * 24 + 8) = v;
            }
        }
        // ---- prefetch next tile's j's (drained at B1 -> ready for issues) ----
        const int nxt = tile + gridDim.x;
        const bool hasn = (nxt < ntiles);
        int jg_n = 0, ja_n = 0, jb_n = 0;
        if (hasn) {
            jg_n = gidx[(nxt * 2 + sm) * NS + sj];
            if constexpr (PIPE) {
                ja_n = gidx[(nxt * 2 + (rowA >> 5)) * NS + (rowA & 31)];
                jb_n = gidx[(nxt * 2 + (rowB >> 5)) * NS + (rowB & 31)];
            }
        }
        __syncthreads();               // B1: XsG visible; j loads drained

        if constexpr (PIPE) {          // issue fb(t+1) -> XsF[nxt]; flies under compute
            if (hasn) {
                gload_lds16(fb + (size_t)ja_n * 64 + uA * 8,
                            XsFn + (wv * 2 + 0) * 512);
                gload_lds16(fb + (size_t)jb_n * 64 + uB * 8,
                            XsFn + (wv * 2 + 1) * 512);
            }
        }

        // ---- conv0: wave's 16 cols x 4 m-tiles, K=96 ----
#pragma unroll 2
        for (int mt = 0; mt < 4; ++mt) {
            const int row = mt * 16 + ln;
            const short* arF = XsFc + row * 64;
            short8 A0 = *(const short8*)(arF + ((kg ^ rs) * 8));
            short8 A1 = *(const short8*)(arF + (((4 + kg) ^ rs) * 8));
            short8 A2 = zero8;
            if (kg < 2)
                A2 = *(const short8*)(XsG + row * 24 + kg * 8);
            f32x4 acc = {bb0, bb0, bb0, bb0};
            acc = __builtin_amdgcn_mfma_f32_16x16x32_bf16(A0, W0[0], acc, 0, 0, 0);
            acc = __builtin_amdgcn_mfma_f32_16x16x32_bf16(A1, W0[1], acc, 0, 0, 0);
            acc = __builtin_amdgcn_mfma_f32_16x16x32_bf16(A2, W0[2], acc, 0, 0, 0);
            if constexpr (STAGE == 0) {
#pragma unroll
                for (int r = 0; r < 4; ++r) {
                    float y = acc[r];
                    ssum[0] += y; ssq[0] += y * y;
                }
            } else {
#pragma unroll
                for (int r = 0; r < 4; ++r) {
                    int rw = mt * 16 + kg * 4 + r;
                    float x1 = fmaxf(a0v * acc[r] + c0v, 0.f);
                    X1s[rw * 64 + ((((chW >> 3) ^ (rw & 7)) << 3) | (chW & 7))] = cvt_bf16(x1);
                }
            }
        }
        if constexpr (STAGE >= 1) {
            __syncthreads();           // X1 complete
            // ---- conv1: K=64 ----
#pragma unroll 2
            for (int mt = 0; mt < 4; ++mt) {
                const short* arow = X1s + (mt * 16 + ln) * 64;
                f32x4 acc = {bb1, bb1, bb1, bb1};
#pragma unroll
                for (int kt = 0; kt < 2; ++kt) {
                    short8 A = *(const short8*)(arow + (((kt*4 + kg) ^ rs) * 8));
                    acc = __builtin_amdgcn_mfma_f32_16x16x32_bf16(A, W1[kt], acc, 0, 0, 0);
                }
                if constexpr (STAGE == 1) {
#pragma unroll
                    for (int r = 0; r < 4; ++r) {
                        float y = acc[r];
                        ssum[0] += y; ssq[0] += y * y;
                    }
                } else {
#pragma unroll
                    for (int r = 0; r < 4; ++r) {
                        int rw = mt * 16 + kg * 4 + r;
                        float x2 = fmaxf(a1v * acc[r] + c1v, 0.f);
                        X2s[rw * 64 + ((((chW >> 3) ^ (rw & 7)) << 3) | (chW & 7))] = cvt_bf16(x2);
                    }
                }
            }
        }
        if constexpr (STAGE == 2) {
            __syncthreads();           // X2 complete
            // ---- conv2: wave's 32 cols, 2 points, stats + max/min ----
#pragma unroll
            for (int p = 0; p < 2; ++p) {
                float mx0 = -3.402823466e38f, mn0 = 3.402823466e38f;
                float mx1 = -3.402823466e38f, mn1 = 3.402823466e38f;
#pragma unroll
                for (int mh = 0; mh < 2; ++mh) {
                    const int mt = p * 2 + mh;
                    const short* arow = X2s + (mt * 16 + ln) * 64;
                    short8 A0 = *(const short8*)(arow + (((kg)     ^ rs) * 8));
                    short8 A1 = *(const short8*)(arow + (((4 + kg) ^ rs) * 8));
                    f32x4 acc = {bb2a, bb2a, bb2a, bb2a};
                    acc = __builtin_amdgcn_mfma_f32_16x16x32_bf16(A0, W2[0][0], acc, 0, 0, 0);
                    acc = __builtin_amdgcn_mfma_f32_16x16x32_bf16(A1, W2[0][1], acc, 0, 0, 0);
#pragma unroll
                    for (int r = 0; r < 4; ++r) {
                        float y = acc[r];
                        ssum[0] += y; ssq[0] += y * y;
                        mx0 = fmaxf(mx0, y); mn0 = fminf(mn0, y);
                    }
                    f32x4 acd = {bb2b, bb2b, bb2b, bb2b};
                    acd = __builtin_amdgcn_mfma_f32_16x16x32_bf16(A0, W2[1][0], acd, 0, 0, 0);
                    acd = __builtin_amdgcn_mfma_f32_16x16x32_bf16(A1, W2[1][1], acd, 0, 0, 0);
#pragma unroll
                    for (int r = 0; r < 4; ++r) {
                        float y = acd[r];
                        ssum[1] += y; ssq[1] += y * y;
                        mx1 = fmaxf(mx1, y); mn1 = fminf(mn1, y);
                    }
                }
                mx0 = fmaxf(mx0, __shfl_xor(mx0, 16)); mn0 = fminf(mn0, __shfl_xor(mn0, 16));
                mx0 = fmaxf(mx0, __shfl_xor(mx0, 32)); mn0 = fminf(mn0, __shfl_xor(mn0, 32));
                mx1 = fmaxf(mx1, __shfl_xor(mx1, 16)); mn1 = fminf(mn1, __shfl_xor(mn1, 16));
                mx1 = fmaxf(mx1, __shfl_xor(mx1, 32)); mn1 = fminf(mn1, __shfl_xor(mn1, 32));
                if (lane < 16) {
                    size_t base = (size_t)(m0 + p) * 128 + wv * 32 + ln;
                    ymax[base]      = mx0; ymin[base]      = mn0;
                    ymax[base + 16] = mx1; ymin[base + 16] = mn1;
                }
            }
        }
        jg = jg_n;
        cur ^= 1;
    }

    // ---- stats epilogue: channels disjoint per wave -> direct write ----
    float* pb = part + (size_t)blockIdx.x * 256;
#pragma unroll
    for (int nt = 0; nt < NT; ++nt) {
        float v = ssum[nt], q = ssq[nt];
        v += __shfl_xor(v, 16); q += __shfl_xor(q, 16);
        v += __shfl_xor(v, 32); q += __shfl_xor(q, 32);
        if (lane < 16) {
            constexpr int NCH = (STAGE == 2) ? 128 : 64;
            int c = (STAGE == 2) ? (wv * 32 + nt * 16 + ln) : (wv * 16 + ln);
            pb[c] = v; pb[NCH + c] = q;
        }
    }
}

__global__ __launch_bounds__(256) void reduce_partials(
    const float* __restrict__ part, float* __restrict__ fstats,
    int base, int nblocks)
{
    __shared__ float red[256];
    int c = blockIdx.x;
    float s = 0.f;
    for (int b = threadIdx.x; b < nblocks; b += 256)
        s += part[(size_t)b * 256 + c];
    red[threadIdx.x] = s;
    __syncthreads();
    for (int off = 128; off > 0; off >>= 1) {
        if (threadIdx.x < off) red[threadIdx.x] += red[threadIdx.x + off];
        __syncthreads();
    }
    if (threadIdx.x == 0) fstats[base + c] = red[0];
}

__global__ __launch_bounds__(256) void final_kernel(
    const float* __restrict__ center, const float* __restrict__ normal,
    const int* __restrict__ offs,
    const float* __restrict__ g2, const float* __restrict__ be2,
    const float* __restrict__ fstats,
    const float* __restrict__ ymax, const float* __restrict__ ymin,
    float* __restrict__ out, int N, float inv_cnt)
{
    int i = blockIdx.x * 256 + threadIdx.x;
    int nc = N * 3;
    int nf = N * 128;
    int total = 2 * nc + nf + 1;
    if (i >= total) return;
    if (i < nc) {
        out[i] = center[i];
    } else if (i < 2 * nc) {
        out[i] = normal[i - nc];
    } else if (i < 2 * nc + nf) {
        int idx = i - 2 * nc;
        int c = idx & 127;
        float mean = fstats[256 + c] * inv_cnt;
        float var  = fstats[384 + c] * inv_cnt - mean * mean;
        float a = g2[c] * rsqrtf(fmaxf(var, 0.f) + BN_EPS);
        float v = (a >= 0.f) ? ymax[idx] : ymin[idx];   // monotone BN+relu
        out[i] = fmaxf(a * (v - mean) + be2[c], 0.f);
    } else {
        out[i] = (float)offs[0];
    }
}

extern "C" void kernel_launch(void* const* d_in, const int* in_sizes, int n_in,
                              void* d_out, int out_size, void* d_ws, size_t ws_size,
                              hipStream_t stream)
{
    const float* center  = (const float*)d_in[0];
    const float* normal  = (const float*)d_in[1];
    const float* feature = (const float*)d_in[2];
    const int*   offs    = (const int*)d_in[3];
    const int*   gidx    = (const int*)d_in[4];
    const float* w0  = (const float*)d_in[5];
    const float* b0  = (const float*)d_in[6];
    const float* g0  = (const float*)d_in[7];
    const float* be0 = (const float*)d_in[8];
    const float* w1  = (const float*)d_in[9];
    const float* b1  = (const float*)d_in[10];
    const float* g1  = (const float*)d_in[11];
    const float* be1 = (const float*)d_in[12];
    const float* w2  = (const float*)d_in[13];
    const float* b2  = (const float*)d_in[14];
    const float* g2  = (const float*)d_in[15];
    const float* be2 = (const float*)d_in[16];

    const int N = in_sizes[0] / 3;
    const int ntiles = N / 2;          // 2 points per tile
    const float inv_cnt = 1.0f / (float)((size_t)N * NS);

    float* out = (float*)d_out;
    float* out_nf = out + (size_t)2 * N * 3;          // ymax in-place in d_out

    float* wsf    = (float*)d_ws;
    float* fstats = wsf;                              // [512]
    float* part   = wsf + 512;                        // [GRID_MAX*256]
    float* ymin   = part + (size_t)GRID_MAX * 256;    // [N*128]
    short* wbase  = (short*)(ymin + (size_t)N * 128);
    short* wf0 = wbase;                // 12*512
    short* wf1 = wf0 + 12 * 512;       // 8*512
    short* wf2 = wf1 + 8 * 512;        // 16*512
    short* wend = wf2 + 16 * 512;

    // gather tables
    short* featbf = wend;                             // [N*64] bf16
    float* cn     = (float*)(featbf + (size_t)N * 64);// [N*8] fp32
    size_t need = (size_t)((char*)(cn + (size_t)N * 8) - (char*)d_ws);
    const bool has_tab = (ws_size >= need);
    const short* fbp = has_tab ? featbf : nullptr;
    const float* cnp = has_tab ? cn : nullptr;

    dim3 blk(256);

    prep_weights<<<dim3(9), blk, 0, stream>>>(w0, w1, w2, wf0, wf1, wf2);
    if (has_tab) {
        int n8 = N * 8;
        feat2bf<<<dim3((n8 + 255) / 256), blk, 0, stream>>>(feature, featbf, n8);
        prep_cn<<<dim3((N + 255) / 256), blk, 0, stream>>>(center, normal, cn, N);
    }

    if (has_tab) {
        stage_kernel<0, true><<<dim3(GRID_S0), blk, 0, stream>>>(center, normal, feature,
            fbp, cnp, gidx, wf0, wf1, wf2, b0, b1, b2,
            g0, be0, g1, be1, fstats, part, out_nf, ymin, ntiles, inv_cnt);
        reduce_partials<<<dim3(128), blk, 0, stream>>>(part, fstats, 0, GRID_S0);

        stage_kernel<1, true><<<dim3(GRID_S1), blk, 0, stream>>>(center, normal, feature,
            fbp, cnp, gidx, wf0, wf1, wf2, b0, b1, b2,
            g0, be0, g1, be1, fstats, part, out_nf, ymin, ntiles, inv_cnt);
        reduce_partials<<<dim3(128), blk, 0, stream>>>(part, fstats, 128, GRID_S1);

        stage_kernel<2, true><<<dim3(GRID_S2), blk, 0, stream>>>(center, normal, feature,
            fbp, cnp, gidx, wf0, wf1, wf2, b0, b1, b2,
            g0, be0, g1, be1, fstats, part, out_nf, ymin, ntiles, inv_cnt);
        reduce_partials<<<dim3(256), blk, 0, stream>>>(part, fstats, 256, GRID_S2);
    } else {
        stage_kernel<0, false><<<dim3(GRID_S0), blk, 0, stream>>>(center, normal, feature,
            fbp, cnp, gidx, wf0, wf1, wf2, b0, b1, b2,
            g0, be0, g1, be1, fstats, part, out_nf, ymin, ntiles, inv_cnt);
        reduce_partials<<<dim3(128), blk, 0, stream>>>(part, fstats, 0, GRID_S0);

        stage_kernel<1, false><<<dim3(GRID_S1), blk, 0, stream>>>(center, normal, feature,
            fbp, cnp, gidx, wf0, wf1, wf2, b0, b1, b2,
            g0, be0, g1, be1, fstats, part, out_nf, ymin, ntiles, inv_cnt);
        reduce_partials<<<dim3(128), blk, 0, stream>>>(part, fstats, 128, GRID_S1);

        stage_kernel<2, false><<<dim3(GRID_S2), blk, 0, stream>>>(center, normal, feature,
            fbp, cnp, gidx, wf0, wf1, wf2, b0, b1, b2,
            g0, be0, g1, be1, fstats, part, out_nf, ymin, ntiles, inv_cnt);
        reduce_partials<<<dim3(256), blk, 0, stream>>>(part, fstats, 256, GRID_S2);
    }

    int total = 2 * N * 3 + N * 128 + 1;
    final_kernel<<<dim3((total + 255) / 256), blk, 0, stream>>>(
        center, normal, offs, g2, be2, fstats, out_nf, ymin, out, N, inv_cnt);
}